// Round 2
// baseline (641.374 us; speedup 1.0000x reference)
//
#include <hip/hip_runtime.h>
#include <hip/hip_cooperative_groups.h>
#include <stdint.h>

namespace cg = cooperative_groups;

#define N_NODES  8192
#define HIDDEN   256
#define HEADS    4
#define HEAD_DIM 64
#define NUM_EDGES 4096
#define NUM_INC  65536
#define LN_EPS   1e-5f

typedef unsigned int uint_t;
typedef float __attribute__((ext_vector_type(4))) f4v;

// Inputs fp32, OUTPUTS fp32 (r11-r16 verified, absmax 0.0156).
// Budget model: ~218-225us fixed harness poison/restore in the timed window
// (fills ran 77-81% HBM this round -> +-7us cross-run noise band).
// This round: ONE cooperative kernel. Eliminates 4 launch gaps + 4 kernel
// tails + 8704-block dispatch overhead; AW/out0 phase becomes a dynamic
// work-stealing loop (atomic counter, out0 tiles claimed first).
// Grid = 4 blocks/CU x 256 CUs = 1024 (guaranteed co-resident:
// __launch_bounds__(256,4) caps VGPR at 128; LDS ~37KB -> 4/CU fits 160KB).

// ---------------- ws layout (bytes) ----------------
#define OFF_SEGSZ    0        // int [4096]     } zeroed in P0
#define OFF_NCNT     16384    // int [8192]     }
#define OFF_NFILL    49152    // int [8192]     }
#define OFF_EFILL    81920    // int [4096]     }
#define OFF_SEGSUM   98304    // float [4096*4] }
#define OFF_CTR      163840   // int work counter (16B reserved) }
#define ZERO_BYTES   163856
#define OFF_VKH      163856   // float [4*256] transposed [h][k]
#define OFF_BL       167952   // float [pad 64B]
#define OFF_LOGIT    168016   // float [8192*4]
#define OFF_NPTR     299088   // int [8193] (+pad -> 32816B)
#define OFF_EPTR     331904   // int [4097] (+pad -> 16448B)
#define OFF_NINC     348352   // int [65536]
#define OFF_EMEM     610496   // int [65536]

#define N_WORK (N_NODES + 512)   // 512 out0 tiles first, then 8192 AW rows

__global__ __launch_bounds__(256, 4) void k_all(
    const float* __restrict__ Ww, const float* __restrict__ Wb,
    const float* __restrict__ ea, const float* __restrict__ x,
    const int* __restrict__ node_idx, const int* __restrict__ edge_idx,
    const float* __restrict__ out_w, const float* __restrict__ out_b,
    char* __restrict__ ws, float* __restrict__ AW, float* __restrict__ out0)
{
    float* vkhT    = (float*)(ws + OFF_VKH);
    float* bl      = (float*)(ws + OFF_BL);
    float* logit   = (float*)(ws + OFF_LOGIT);
    int*   seg_size  = (int*)(ws + OFF_SEGSZ);
    int*   node_cnt  = (int*)(ws + OFF_NCNT);
    int*   node_fill = (int*)(ws + OFF_NFILL);
    int*   edge_fill = (int*)(ws + OFF_EFILL);
    float* seg_sum   = (float*)(ws + OFF_SEGSUM);
    int*   node_ptr  = (int*)(ws + OFF_NPTR);
    int*   edge_ptr  = (int*)(ws + OFF_EPTR);
    int*   node_inc  = (int*)(ws + OFF_NINC);
    int*   edge_mem  = (int*)(ws + OFF_EMEM);
    int*   wctr      = (int*)(ws + OFF_CTR);

    // Unioned LDS: P1 x-stage (9220 floats) is the max; AW row (8192) and
    // out0 y[16][260] (4160) alias the same buffer.
    __shared__ __align__(16) float smem[9232];
    __shared__ float sr[16], mu_s[16], rs_s[16];
    __shared__ int wks;

    cg::grid_group gg = cg::this_grid();
    int t = threadIdx.x, b = blockIdx.x;
    int nb = gridDim.x;
    int w = t >> 6, lane = t & 63;

    // ---- P0: zero accumulators + counter; blocks 0..3 fold W_w/W_b with ea
    for (int g = b * 256 + t; g < ZERO_BYTES / 4; g += nb * 256)
        ((uint_t*)ws)[g] = 0u;
    if (b < HEADS) {
        int k = t, h = b;
        float a = 0.f;
        for (int d = 0; d < HEAD_DIM; ++d)
            a += ea[h * HEAD_DIM + d] * Ww[(size_t)(h * HEAD_DIM + d) * HIDDEN + k];
        vkhT[h * HIDDEN + k] = a;
        if (k == 0) {
            float s = 0.f;
            for (int d = 0; d < HEAD_DIM; ++d)
                s += Wb[h * HEAD_DIM + d] * ea[h * HEAD_DIM + d];
            bl[h] = s;
        }
    }
    gg.sync();

    // ---- P1: logits (blocks 0..255, 32 nodes each) + histogram atomics
    if (b < 256) {
        int i = b * 256 + t;
        atomicAdd(&seg_size[edge_idx[i]], 1);
        atomicAdd(&node_cnt[node_idx[i]], 1);
        float* xs  = smem;          // 8192 floats
        float* vs  = smem + 8192;   // 1024 floats
        float* bls = smem + 9216;   // 4 floats
        float4* xsv = (float4*)xs;
        const float4* xg = (const float4*)(x + (size_t)b * 32 * HIDDEN);
        #pragma unroll
        for (int c = 0; c < 8; ++c) xsv[c * 256 + t] = xg[c * 256 + t];
        ((float4*)vs)[t] = ((const float4*)vkhT)[t];
        if (t < HEADS) bls[t] = bl[t];
        __syncthreads();
        if (t < 128) {
            int n = t >> 2, h = t & 3;
            const float4* xr = (const float4*)(xs + n * HIDDEN);
            const float4* vr = (const float4*)(vs + h * HIDDEN);
            float acc = bls[h];
            for (int k4 = 0; k4 < HIDDEN / 4; ++k4) {
                float4 xv = xr[k4], vv = vr[k4];
                acc += xv.x * vv.x + xv.y * vv.y + xv.z * vv.z + xv.w * vv.w;
            }
            logit[(b * 32 + n) * HEADS + h] = acc;
        }
    }
    gg.sync();

    // ---- P2: exclusive scans (blocks 0,1)
    if (b < 2) {
        int* part = (int*)smem;
        const int* cnt; int* ptr; int n;
        if (b == 0) { cnt = node_cnt; ptr = node_ptr; n = N_NODES; }
        else        { cnt = seg_size; ptr = edge_ptr; n = NUM_EDGES; }
        int C = n / 256;
        int s = 0;
        for (int j = 0; j < C; ++j) s += cnt[t * C + j];
        part[t] = s;
        __syncthreads();
        if (t == 0) {
            int run = 0;
            for (int i = 0; i < 256; ++i) { int tmp = part[i]; part[i] = run; run += tmp; }
            ptr[n] = run;
        }
        __syncthreads();
        int run = part[t];
        for (int j = 0; j < C; ++j) { ptr[t * C + j] = run; run += cnt[t * C + j]; }
    }
    gg.sync();

    // ---- P3: fill CSRs + accumulate seg_sum (blocks 0..255)
    if (b < 256) {
        int i = b * 256 + t;
        int n = node_idx[i], e = edge_idx[i];
        int p = node_ptr[n] + atomicAdd(&node_fill[n], 1);
        node_inc[p] = i;
        int q = edge_ptr[e] + atomicAdd(&edge_fill[e], 1);
        edge_mem[q] = n;
        const float4 lg = *(const float4*)(logit + (size_t)n * 4);
        atomicAdd(&seg_sum[e * 4 + 0], __expf(lg.x));
        atomicAdd(&seg_sum[e * 4 + 1], __expf(lg.y));
        atomicAdd(&seg_sum[e * 4 + 2], __expf(lg.z));
        atomicAdd(&seg_sum[e * 4 + 3], __expf(lg.w));
    }
    gg.sync();

    // ---- P4: dynamic work loop. Items 0..511 = out0 tiles (claimed first,
    // GEMM overlaps AW store storm); items 512..8703 = AW row item-512.
    for (;;) {
        __syncthreads();                       // protect LDS reuse across items
        if (t == 0) wks = atomicAdd(wctr, 1);
        __syncthreads();
        int wk = wks;
        if (wk >= N_WORK) break;

        if (wk >= 512) {
            // ---- AW row i ----
            int i = wk - 512;
            int pb = node_ptr[i], pe = node_ptr[i + 1];
            const float4 lg = *(const float4*)(logit + (size_t)i * 4);
            float ex0 = __expf(lg.x), ex1 = __expf(lg.y);
            float ex2 = __expf(lg.z), ex3 = __expf(lg.w);
            float* buf = smem;
            float4* rowv = (float4*)buf;
            #pragma unroll
            for (int c = 0; c < 8; ++c) rowv[c * 256 + t] = make_float4(0.f, 0.f, 0.f, 0.f);
            int p = pb + w;                    // 4 parallel wave chains
            int m_nxt = (p < pe) ? node_inc[p] : 0;
            __syncthreads();
            for (; p < pe; p += 4) {
                int m = m_nxt;
                if (p + 4 < pe) m_nxt = node_inc[p + 4];
                int e = edge_idx[m];
                int qb = edge_ptr[e], qe = edge_ptr[e + 1];
                if (qe - qb >= 2) {
                    const float4 ss = *(const float4*)(seg_sum + (size_t)e * 4);
                    float a = 0.25f * (ex0 / ss.x + ex1 / ss.y + ex2 / ss.z + ex3 / ss.w);
                    for (int q = qb + lane; q < qe; q += 64)
                        atomicAdd(&buf[edge_mem[q]], a);
                }
            }
            __syncthreads();
            if (t == 0) buf[i] = 0.f;          // zero diagonal
            __syncthreads();
            f4v* dst = (f4v*)(AW + (size_t)i * N_NODES);
            #pragma unroll
            for (int c = 0; c < 8; ++c)
                __builtin_nontemporal_store(((const f4v*)rowv)[c * 256 + t], &dst[c * 256 + t]);
            continue;
        }

        // ---- out0 tile rows [wk*16, wk*16+16) ----
        float (*y)[260] = (float (*)[260])smem;
        int R = wk * 16;
        {
            int nl = t >> 4, s = t & 15;       // 16 threads per node
            int n = R + nl;
            int nbg = node_ptr[n], ne = node_ptr[n + 1];
            const float4 lg = *(const float4*)(logit + (size_t)n * 4);
            float ex0 = __expf(lg.x), ex1 = __expf(lg.y);
            float ex2 = __expf(lg.z), ex3 = __expf(lg.w);
            float wsum = 0.f;
            for (int p = nbg + s; p < ne; p += 16) {
                int m = node_inc[p];
                int e = edge_idx[m];
                int qb = edge_ptr[e], qe = edge_ptr[e + 1];
                if (qe - qb >= 2) {
                    const float4 ss = *(const float4*)(seg_sum + (size_t)e * 4);
                    wsum += 0.25f * (ex0 / ss.x + ex1 / ss.y + ex2 / ss.z + ex3 / ss.w);
                }
            }
            #pragma unroll
            for (int off = 1; off < 16; off <<= 1) wsum += __shfl_xor(wsum, off, 64);
            if (s == 0) {
                int c = ne - nbg; if (c < 1) c = 1;
                sr[nl] = wsum / (float)c;
            }
        }
        __syncthreads();
        #pragma unroll
        for (int r = 0; r < 16; ++r)
            y[r][t] = sr[r] * x[(size_t)(R + r) * HIDDEN + t];
        __syncthreads();
        float acc[16];
        float bias = out_b[t];
        #pragma unroll
        for (int r = 0; r < 16; ++r) acc[r] = bias;
        const float4* wr4 = (const float4*)(out_w + (size_t)t * HIDDEN);
        for (int j4 = 0; j4 < HIDDEN / 4; ++j4) {
            float4 wv = wr4[j4];
            #pragma unroll
            for (int r = 0; r < 16; ++r) {
                float4 yv = *(const float4*)&y[r][j4 * 4];
                acc[r] += yv.x * wv.x + yv.y * wv.y + yv.z * wv.z + yv.w * wv.w;
            }
        }
        __syncthreads();
        #pragma unroll
        for (int r = 0; r < 16; ++r) y[r][t] = acc[r];
        __syncthreads();
        #pragma unroll
        for (int rr = 0; rr < 4; ++rr) {
            int r = (w << 2) | rr;
            float v = y[r][lane] + y[r][lane + 64] + y[r][lane + 128] + y[r][lane + 192];
            #pragma unroll
            for (int off = 32; off; off >>= 1) v += __shfl_down(v, off, 64);
            float mu = __shfl(v, 0, 64) * (1.0f / HIDDEN);
            float d0 = y[r][lane] - mu, d1 = y[r][lane + 64] - mu;
            float d2 = y[r][lane + 128] - mu, d3 = y[r][lane + 192] - mu;
            float s2 = d0 * d0 + d1 * d1 + d2 * d2 + d3 * d3;
            #pragma unroll
            for (int off = 32; off; off >>= 1) s2 += __shfl_down(s2, off, 64);
            if (lane == 0) {
                mu_s[r] = mu;
                rs_s[r] = rsqrtf(s2 * (1.0f / HIDDEN) + LN_EPS);
            }
        }
        __syncthreads();
        #pragma unroll
        for (int r = 0; r < 16; ++r)
            out0[(size_t)(R + r) * HIDDEN + t] = (y[r][t] - mu_s[r]) * rs_s[r];
    }
}

extern "C" void kernel_launch(void* const* d_in, const int* in_sizes, int n_in,
                              void* d_out, int out_size, void* d_ws, size_t ws_size,
                              hipStream_t stream) {
    const float* x        = (const float*)d_in[0];
    const int*   node_idx = (const int*)d_in[1];
    const int*   edge_idx = (const int*)d_in[2];
    const float* Ww       = (const float*)d_in[3];
    const float* Wb       = (const float*)d_in[4];
    const float* ea       = (const float*)d_in[5];
    const float* ow       = (const float*)d_in[6];
    const float* ob       = (const float*)d_in[7];
    float* out0 = (float*)d_out;
    float* aw   = out0 + (size_t)N_NODES * HIDDEN;
    char*  ws   = (char*)d_ws;

    // Co-residency: query occupancy once, clamp to [256, 1024].
    static int nblk = 0;
    if (nblk == 0) {
        int nper = 0;
        hipOccupancyMaxActiveBlocksPerMultiprocessor(&nper, k_all, 256, 0);
        if (nper < 1) nper = 1;
        if (nper > 4) nper = 4;
        nblk = nper * 256;
    }

    void* args[] = {
        (void*)&Ww, (void*)&Wb, (void*)&ea, (void*)&x,
        (void*)&node_idx, (void*)&edge_idx, (void*)&ow, (void*)&ob,
        (void*)&ws, (void*)&aw, (void*)&out0
    };
    hipLaunchCooperativeKernel((void*)k_all, dim3(nblk), dim3(256), args, 0, stream);
}

// Round 3
// 358.416 us; speedup vs baseline: 1.7895x; 1.7895x over previous
//
#include <hip/hip_runtime.h>
#include <stdint.h>

#define N_NODES  8192
#define HIDDEN   256
#define HEADS    4
#define HEAD_DIM 64
#define NUM_EDGES 4096
#define NUM_INC  65536
#define LN_EPS   1e-5f

typedef unsigned int uint_t;
typedef float __attribute__((ext_vector_type(4))) f4v;

// Inputs fp32, OUTPUTS fp32 (r11-r16 verified, absmax 0.0156).
// ROUND 2 POST-MORTEM: cooperative single-kernel = 585us catastrophe.
// Root cause: __syncthreads() in the persistent work loop emits
// s_waitcnt vmcnt(0) -> each block drains its 32KB NT-store burst to HBM
// before claiming the next AW row (vmcnt is FIFO, so even next-row gathers
// stall behind stores). Multi-kernel never pays this: a block ENDS after
// issuing stores; block retirement doesn't drain vmcnt, so the 8704-block
// dispatch itself is the store/gather pipeline. REVERTED to 5-kernel
// structure + latency micro-fixes (fold-loop unroll, vectorized scan).

// ---------------- ws layout (bytes) ----------------
#define OFF_SEGSZ    0        // int [4096]     } zeroed by k_foldzero
#define OFF_NCNT     16384    // int [8192]     }
#define OFF_NFILL    49152    // int [8192]     }
#define OFF_EFILL    81920    // int [4096]     }
#define OFF_SEGSUM   98304    // float [4096*4] }  (zero-init for atomics)
#define ZERO_BYTES   163840
#define OFF_VKH      163840   // float [4*256] transposed [h][k]
#define OFF_BL       167936   // float [pad]
#define OFF_LOGIT    168192   // float [8192*4]
#define OFF_NPTR     299264   // int [8193] (+pad)
#define OFF_EPTR     332288   // int [4097] (+pad)
#define OFF_NINC     348928   // int [65536]
#define OFF_EMEM     611072   // int [65536]

// K1: zero accumulators (160 blocks); blocks 0..3 also fold W_w/W_b with ea.
__global__ __launch_bounds__(256) void k_foldzero(const float* __restrict__ Ww,
                                                  const float* __restrict__ Wb,
                                                  const float* __restrict__ ea,
                                                  float* __restrict__ vkhT,
                                                  float* __restrict__ bl,
                                                  uint_t* __restrict__ zw) {
    int t = threadIdx.x, b = blockIdx.x;
    zw[b * 256 + t] = 0u;
    if (b < HEADS) {
        int k = t, h = b;
        float a = 0.f;
        #pragma unroll 8                       // 8 Ww loads in flight (critical path)
        for (int d = 0; d < HEAD_DIM; ++d)
            a += ea[h * HEAD_DIM + d] * Ww[(size_t)(h * HEAD_DIM + d) * HIDDEN + k];
        vkhT[h * HIDDEN + k] = a;
        if (k == 0) {
            float s = 0.f;
            #pragma unroll 8
            for (int d = 0; d < HEAD_DIM; ++d)
                s += Wb[h * HEAD_DIM + d] * ea[h * HEAD_DIM + d];
            bl[h] = s;
        }
    }
}

// K2: logits (256 blocks x 32 nodes) + independent histogram atomics folded in.
__global__ __launch_bounds__(256) void k_logits(const float* __restrict__ x,
                                                const float* __restrict__ vkhT,
                                                const float* __restrict__ bl,
                                                const int* __restrict__ node_idx,
                                                const int* __restrict__ edge_idx,
                                                int* __restrict__ seg_size,
                                                int* __restrict__ node_cnt,
                                                float* __restrict__ logit) {
    __shared__ __align__(16) float xs[32 * HIDDEN];
    __shared__ __align__(16) float vs[HEADS * HIDDEN];
    __shared__ float bls[HEADS];
    int t = threadIdx.x, b = blockIdx.x;
    {
        int i = b * 256 + t;
        atomicAdd(&seg_size[edge_idx[i]], 1);
        atomicAdd(&node_cnt[node_idx[i]], 1);
    }
    float4* xsv = (float4*)xs;
    const float4* xg = (const float4*)(x + (size_t)b * 32 * HIDDEN);
    #pragma unroll
    for (int i = 0; i < 8; ++i) xsv[i * 256 + t] = xg[i * 256 + t];
    ((float4*)vs)[t] = ((const float4*)vkhT)[t];
    if (t < HEADS) bls[t] = bl[t];
    __syncthreads();
    if (t < 128) {
        int n = t >> 2, h = t & 3;
        const float4* xr = (const float4*)(xs + n * HIDDEN);
        const float4* vr = (const float4*)(vs + h * HIDDEN);
        float acc = bls[h];
        for (int k4 = 0; k4 < HIDDEN / 4; ++k4) {
            float4 xv = xr[k4], vv = vr[k4];
            acc += xv.x * vv.x + xv.y * vv.y + xv.z * vv.z + xv.w * vv.w;
        }
        logit[(b * 32 + n) * HEADS + h] = acc;
    }
}

// K3: exclusive scans (vectorized int4 loads, counts kept in registers).
template<int C>
__device__ __forceinline__ void scan_body(const int* __restrict__ cnt,
                                          int* __restrict__ ptr, int n,
                                          int t, int* part) {
    int4 v[C / 4];
    const int4* c4 = (const int4*)(cnt + t * C);
    int s = 0;
    #pragma unroll
    for (int j = 0; j < C / 4; ++j) {
        v[j] = c4[j];
        s += v[j].x + v[j].y + v[j].z + v[j].w;
    }
    part[t] = s;
    __syncthreads();
    if (t == 0) {
        int run = 0;
        #pragma unroll 8
        for (int i = 0; i < 256; ++i) { int tmp = part[i]; part[i] = run; run += tmp; }
        ptr[n] = run;
    }
    __syncthreads();
    int run = part[t];
    int* p = ptr + t * C;
    #pragma unroll
    for (int j = 0; j < C / 4; ++j) {
        p[j * 4 + 0] = run; run += v[j].x;
        p[j * 4 + 1] = run; run += v[j].y;
        p[j * 4 + 2] = run; run += v[j].z;
        p[j * 4 + 3] = run; run += v[j].w;
    }
}

__global__ __launch_bounds__(256) void k_scan(const int* __restrict__ node_cnt, int* __restrict__ node_ptr,
                                              const int* __restrict__ seg_size, int* __restrict__ edge_ptr) {
    __shared__ int part[256];
    int t = threadIdx.x;
    if (blockIdx.x == 0) scan_body<N_NODES / 256>(node_cnt, node_ptr, N_NODES, t, part);
    else                 scan_body<NUM_EDGES / 256>(seg_size, edge_ptr, NUM_EDGES, t, part);
}

// K4: fill CSRs + accumulate seg_sum (logit complete; n,e already in regs).
__global__ void k_fill(const int* __restrict__ node_idx, const int* __restrict__ edge_idx,
                       const int* __restrict__ node_ptr, const int* __restrict__ edge_ptr,
                       int* __restrict__ node_fill, int* __restrict__ edge_fill,
                       int* __restrict__ node_inc, int* __restrict__ edge_mem,
                       const float* __restrict__ logit, float* __restrict__ seg_sum) {
    int i = blockIdx.x * 256 + threadIdx.x;
    int n = node_idx[i], e = edge_idx[i];
    int p = node_ptr[n] + atomicAdd(&node_fill[n], 1);
    node_inc[p] = i;
    int q = edge_ptr[e] + atomicAdd(&edge_fill[e], 1);
    edge_mem[q] = n;
    const float4 lg = *(const float4*)(logit + (size_t)n * 4);
    atomicAdd(&seg_sum[e * 4 + 0], __expf(lg.x));
    atomicAdd(&seg_sum[e * 4 + 1], __expf(lg.y));
    atomicAdd(&seg_sum[e * 4 + 2], __expf(lg.z));
    atomicAdd(&seg_sum[e * 4 + 3], __expf(lg.w));
}

// K5 (role-split, 8704 blocks): blocks 0..511 = out0 tiles (launch first,
// GEMM overlaps the AW store storm); blocks 512..8703 = AW row b-512.
// One row per block is deliberate: block retirement after the NT-store burst
// is what pipelines store-drain against the next block's gathers (r2 lesson).
__global__ __launch_bounds__(256) void k_aw_out(const int* __restrict__ node_ptr,
                                                const int* __restrict__ node_inc,
                                                const int* __restrict__ edge_idx,
                                                const int* __restrict__ edge_ptr,
                                                const int* __restrict__ edge_mem,
                                                const float* __restrict__ logit,
                                                const float* __restrict__ seg_sum,
                                                const float* __restrict__ x,
                                                const float* __restrict__ out_w,
                                                const float* __restrict__ out_b,
                                                float* __restrict__ AW,
                                                float* __restrict__ out0) {
    __shared__ __align__(16) float buf[N_NODES];   // 32 KB (row OR y[16][260])
    __shared__ float sr[16], mu_s[16], rs_s[16];
    int t = threadIdx.x, w = t >> 6, lane = t & 63;
    int b = blockIdx.x;

    if (b >= 512) {
        // ---- AW row i ----
        int i = b - 512;
        int pb = node_ptr[i], pe = node_ptr[i + 1];
        const float4 lg = *(const float4*)(logit + (size_t)i * 4);
        float ex0 = __expf(lg.x), ex1 = __expf(lg.y);
        float ex2 = __expf(lg.z), ex3 = __expf(lg.w);
        float4* rowv = (float4*)buf;
        #pragma unroll
        for (int c = 0; c < 8; ++c) rowv[c * 256 + t] = make_float4(0.f, 0.f, 0.f, 0.f);
        int p = pb + w;                            // 4 parallel wave chains
        int m_nxt = (p < pe) ? node_inc[p] : 0;    // pipeline the index gather
        __syncthreads();
        for (; p < pe; p += 4) {
            int m = m_nxt;
            if (p + 4 < pe) m_nxt = node_inc[p + 4];
            int e = edge_idx[m];
            int qb = edge_ptr[e], qe = edge_ptr[e + 1];
            if (qe - qb >= 2) {
                const float4 ss = *(const float4*)(seg_sum + (size_t)e * 4);
                float a = 0.25f * (ex0 / ss.x + ex1 / ss.y + ex2 / ss.z + ex3 / ss.w);
                for (int q = qb + lane; q < qe; q += 64)
                    atomicAdd(&buf[edge_mem[q]], a);
            }
        }
        __syncthreads();
        if (t == 0) buf[i] = 0.f;                  // zero diagonal
        __syncthreads();
        f4v* dst = (f4v*)(AW + (size_t)i * N_NODES);
        #pragma unroll
        for (int c = 0; c < 8; ++c)
            __builtin_nontemporal_store(((const f4v*)rowv)[c * 256 + t], &dst[c * 256 + t]);
        return;
    }

    // ---- out0 tile rows [b*16, b*16+16) ----
    float (*y)[260] = (float (*)[260])buf;
    int R = b * 16;
    {
        int nl = t >> 4, s = t & 15;               // 16 threads per node
        int n = R + nl;
        int nb = node_ptr[n], ne = node_ptr[n + 1];
        const float4 lg = *(const float4*)(logit + (size_t)n * 4);
        float ex0 = __expf(lg.x), ex1 = __expf(lg.y);
        float ex2 = __expf(lg.z), ex3 = __expf(lg.w);
        float wsum = 0.f;
        for (int p = nb + s; p < ne; p += 16) {
            int m = node_inc[p];
            int e = edge_idx[m];
            int qb = edge_ptr[e], qe = edge_ptr[e + 1];
            if (qe - qb >= 2) {
                const float4 ss = *(const float4*)(seg_sum + (size_t)e * 4);
                wsum += 0.25f * (ex0 / ss.x + ex1 / ss.y + ex2 / ss.z + ex3 / ss.w);
            }
        }
        #pragma unroll
        for (int off = 1; off < 16; off <<= 1) wsum += __shfl_xor(wsum, off, 64);
        if (s == 0) {
            int c = ne - nb; if (c < 1) c = 1;
            sr[nl] = wsum / (float)c;
        }
    }
    __syncthreads();
    #pragma unroll
    for (int r = 0; r < 16; ++r)
        y[r][t] = sr[r] * x[(size_t)(R + r) * HIDDEN + t];
    __syncthreads();
    float acc[16];
    float bias = out_b[t];
    #pragma unroll
    for (int r = 0; r < 16; ++r) acc[r] = bias;
    const float4* wr4 = (const float4*)(out_w + (size_t)t * HIDDEN);
    for (int j4 = 0; j4 < HIDDEN / 4; ++j4) {
        float4 wv = wr4[j4];
        #pragma unroll
        for (int r = 0; r < 16; ++r) {
            float4 yv = *(const float4*)&y[r][j4 * 4];
            acc[r] += yv.x * wv.x + yv.y * wv.y + yv.z * wv.z + yv.w * wv.w;
        }
    }
    __syncthreads();
    #pragma unroll
    for (int r = 0; r < 16; ++r) y[r][t] = acc[r];
    __syncthreads();
    #pragma unroll
    for (int rr = 0; rr < 4; ++rr) {
        int r = (w << 2) | rr;
        float v = y[r][lane] + y[r][lane + 64] + y[r][lane + 128] + y[r][lane + 192];
        #pragma unroll
        for (int off = 32; off; off >>= 1) v += __shfl_down(v, off, 64);
        float mu = __shfl(v, 0, 64) * (1.0f / HIDDEN);
        float d0 = y[r][lane] - mu, d1 = y[r][lane + 64] - mu;
        float d2 = y[r][lane + 128] - mu, d3 = y[r][lane + 192] - mu;
        float s2 = d0 * d0 + d1 * d1 + d2 * d2 + d3 * d3;
        #pragma unroll
        for (int off = 32; off; off >>= 1) s2 += __shfl_down(s2, off, 64);
        if (lane == 0) {
            mu_s[r] = mu;
            rs_s[r] = rsqrtf(s2 * (1.0f / HIDDEN) + LN_EPS);
        }
    }
    __syncthreads();
    #pragma unroll
    for (int r = 0; r < 16; ++r)
        out0[(size_t)(R + r) * HIDDEN + t] = (y[r][t] - mu_s[r]) * rs_s[r];
}

extern "C" void kernel_launch(void* const* d_in, const int* in_sizes, int n_in,
                              void* d_out, int out_size, void* d_ws, size_t ws_size,
                              hipStream_t stream) {
    const float* x        = (const float*)d_in[0];
    const int*   node_idx = (const int*)d_in[1];
    const int*   edge_idx = (const int*)d_in[2];
    const float* Ww       = (const float*)d_in[3];
    const float* Wb       = (const float*)d_in[4];
    const float* ea       = (const float*)d_in[5];
    const float* ow       = (const float*)d_in[6];
    const float* ob       = (const float*)d_in[7];
    float* out0 = (float*)d_out;
    float* aw   = out0 + (size_t)N_NODES * HIDDEN;

    char* ws = (char*)d_ws;
    int*    seg_size  = (int*)(ws + OFF_SEGSZ);
    int*    node_cnt  = (int*)(ws + OFF_NCNT);
    int*    node_fill = (int*)(ws + OFF_NFILL);
    int*    edge_fill = (int*)(ws + OFF_EFILL);
    float*  seg_sum   = (float*)(ws + OFF_SEGSUM);
    float*  vkhT      = (float*)(ws + OFF_VKH);
    float*  bl        = (float*)(ws + OFF_BL);
    float*  logit     = (float*)(ws + OFF_LOGIT);
    int*    node_ptr  = (int*)(ws + OFF_NPTR);
    int*    edge_ptr  = (int*)(ws + OFF_EPTR);
    int*    node_inc  = (int*)(ws + OFF_NINC);
    int*    edge_mem  = (int*)(ws + OFF_EMEM);

    k_foldzero<<<ZERO_BYTES / 4 / 256, 256, 0, stream>>>(Ww, Wb, ea, vkhT, bl, (uint_t*)ws);
    k_logits<<<N_NODES / 32, 256, 0, stream>>>(x, vkhT, bl, node_idx, edge_idx,
                                               seg_size, node_cnt, logit);
    k_scan<<<2, 256, 0, stream>>>(node_cnt, node_ptr, seg_size, edge_ptr);
    k_fill<<<NUM_INC / 256, 256, 0, stream>>>(node_idx, edge_idx, node_ptr, edge_ptr,
                                              node_fill, edge_fill, node_inc, edge_mem,
                                              logit, seg_sum);
    k_aw_out<<<N_NODES + 512, 256, 0, stream>>>(node_ptr, node_inc, edge_idx, edge_ptr,
                                                edge_mem, logit, seg_sum, x, ow, ob, aw, out0);
}